// Round 12
// baseline (1723.256 us; speedup 1.0000x reference)
//
#include <hip/hip_runtime.h>
#include <hip/hip_bf16.h>

#define GN 65536
#define GE 131072
#define GB 2048

typedef __attribute__((ext_vector_type(8))) short short8;
typedef __attribute__((ext_vector_type(4))) float floatx4;

static __device__ __forceinline__ float sigm(float x) { return 1.0f / (1.0f + __expf(-x)); }
static __device__ __forceinline__ float bf2f(unsigned short u) {
    union { unsigned int i; float f; } v; v.i = ((unsigned int)u) << 16; return v.f;
}
static __device__ __forceinline__ int geti(const void* p, long long i, int f64) {
    return f64 ? (int)((const long long*)p)[i] : ((const int*)p)[i];
}

// ---- merged detectors: blocks 0-16 float-dtype, 17 edge-i64, 18 graph-i64 ----
struct DetectArgs { const void* src[17]; int nhalf[17]; int fi[17]; };
__global__ void k_detect(DetectArgs a, const unsigned int* __restrict__ pe,
                         const unsigned int* __restrict__ pg,
                         int* __restrict__ flags, int* __restrict__ flagE,
                         int* __restrict__ flagG) {
    __shared__ unsigned int sA[256], sB[256];
    if (blockIdx.x >= 17) {
        const unsigned int* p = (blockIdx.x == 17) ? pe : pg;
        const long long nwords = (blockIdx.x == 17) ? (long long)2 * GE : (long long)GN;
        const long long lim = nwords < 16384 ? nwords : 16384;
        unsigned int acc = 0;
        for (long long w = 1 + 2 * (long long)threadIdx.x; w < lim; w += 512) acc |= p[w];
        sA[threadIdx.x] = acc;
        __syncthreads();
        for (int st = 128; st > 0; st >>= 1) {
            if (threadIdx.x < st) sA[threadIdx.x] |= sA[threadIdx.x + st];
            __syncthreads();
        }
        if (threadIdx.x == 0) *((blockIdx.x == 17) ? flagE : flagG) = (sA[0] == 0u) ? 1 : 0;
        return;
    }
    const unsigned short* p = (const unsigned short*)a.src[blockIdx.x];
    const int n0 = a.nhalf[blockIdx.x];
    const int n = n0 < 16384 ? n0 : 16384;
    unsigned int any = 0, orEven = 0;
    for (int i = threadIdx.x; i < n; i += 256) {
        const unsigned short u = p[i];
        const float av = fabsf(bf2f(u));
        if (!(av <= 1e6f)) any = 1u;
        if ((i & 1) == 0) orEven |= u;
    }
    sA[threadIdx.x] = any; sB[threadIdx.x] = orEven;
    __syncthreads();
    for (int s = 128; s > 0; s >>= 1) {
        if (threadIdx.x < s) {
            sA[threadIdx.x] |= sA[threadIdx.x + s];
            sB[threadIdx.x] |= sB[threadIdx.x + s];
        }
        __syncthreads();
    }
    if (threadIdx.x == 0) flags[a.fi[blockIdx.x]] = (sA[0] || sB[0] == 0u) ? 1 : 0;
}

// ---- batched f32 canonicalization (14 tensors; dead w2->F[8] conversion dropped) ----
struct CvtArgs { const void* src[15]; float* dst[15]; int n[15]; int fi[15]; int pre[16]; };
__global__ void k_cvt_all(CvtArgs a, const int* __restrict__ flags) {
    const int b = blockIdx.x;
    int t = 0;
    while (t < 14 && b >= a.pre[t + 1]) ++t;
    const int i = (b - a.pre[t]) * 256 + threadIdx.x;
    if (i >= a.n[t]) return;
    const int f = flags[a.fi[t]];
    a.dst[t][i] = f ? ((const float*)a.src[t])[i] : bf2f(((const unsigned short*)a.src[t])[i]);
}

// repack w2 [128][4096] -> w2P bf16, COALESCED-FRAGMENT layout:
// group g = ((t*4 + kk)*8 + rb); each wave fragment load is one contiguous 1KB segment.
__global__ __launch_bounds__(256) void k_t2(const void* __restrict__ src,
                                            __hip_bfloat16* __restrict__ w2P,
                                            const int* __restrict__ flag) {
    const int tid8 = blockIdx.x * 256 + threadIdx.x;   // 65536 producers of 8 elems
    const int quad = tid8 & 3, lr = (tid8 >> 2) & 15, rb = (tid8 >> 6) & 7,
              kk = (tid8 >> 9) & 3, t = tid8 >> 11;
    const int n = t * 128 + rb * 16 + lr;              // output col 0..4095
    const int k0 = kk * 32 + quad * 8;                 // k 0..127
    const int isf32 = *flag;
    short8 v;
    #pragma unroll
    for (int j = 0; j < 8; ++j) {
        const size_t si = (size_t)(k0 + j) * 4096 + n;
        const float f = isf32 ? ((const float*)src)[si] : bf2f(((const unsigned short*)src)[si]);
        const __hip_bfloat16 b = __float2bfloat16(f);
        v[j] = *(const short*)&b;
    }
    *(short8*)(w2P + (size_t)tid8 * 8) = v;
}

// pack GRU weights into MFMA B-fragment layout, hi/lo bf16 split.
__global__ void k_gpack2(const float* __restrict__ w_ih, const float* __restrict__ w_hh,
                         __hip_bfloat16* __restrict__ gwp) {
    const int t = blockIdx.x * 256 + threadIdx.x;
    if (t >= 3072) return;
    const int lane = t & 63;
    const int kk = (t >> 6) & 1;
    const int nb = (t >> 7) % 12;
    const int mat = t / 1536;
    const float* W = mat ? w_hh : w_ih;          // [192][64]
    const int c = nb * 16 + (lane & 15);
    const int k0 = kk * 32 + (lane >> 4) * 8;
    short8 hi, lo;
    #pragma unroll
    for (int j = 0; j < 8; ++j) {
        const float v = W[c * 64 + k0 + j];
        const __hip_bfloat16 bh = __float2bfloat16(v);
        hi[j] = *(const short*)&bh;
        const __hip_bfloat16 bl = __float2bfloat16(v - __bfloat162float(bh));
        lo[j] = *(const short*)&bl;
    }
    const size_t base = (size_t)(((mat * 12 + nb) * 2 + kk) * 2);
    *(short8*)(gwp + (base + 0) * 512 + lane * 8) = hi;
    *(short8*)(gwp + (base + 1) * 512 + lane * 8) = lo;
}

// merged: blocks 0..511 = edge-count atomics; blocks 512+ = rowptr binary search
__global__ void k_cnt_rp(const void* __restrict__ eidx, const void* __restrict__ gi,
                         const int* __restrict__ flagE, const int* __restrict__ flagG,
                         float* __restrict__ counts, int* __restrict__ rowptr) {
    if (blockIdx.x < 512) {
        const int e = blockIdx.x * 256 + threadIdx.x;
        atomicAdd(&counts[geti(eidx, (long long)GE + e, *flagE)], 1.0f);
        return;
    }
    const int g = (blockIdx.x - 512) * 256 + threadIdx.x;
    if (g > GB) return;
    const int f64 = *flagG;
    int lo = 0, hi = GN;
    while (lo < hi) { int mid = (lo + hi) >> 1; if (geti(gi, mid, f64) < g) lo = mid + 1; else hi = mid; }
    rowptr[g] = lo;
}

// lin0: out = relu(nf @ lin0_w + b); 16 nodes/block, whole w staged in LDS
__global__ __launch_bounds__(256) void k_lin0(const void* __restrict__ nf_raw,
                                              const float* __restrict__ w,
                                              const float* __restrict__ b,
                                              float* __restrict__ out,
                                              const int* __restrict__ flag) {
    __shared__ float sw[75][66];
    __shared__ float snf[16][76];
    const int tid = threadIdx.x;
    const int isf32 = *flag;
    const int nb0 = blockIdx.x * 16;
    for (int i = tid; i < 75 * 64; i += 256) sw[i >> 6][i & 63] = w[i];
    for (int i = tid; i < 16 * 75; i += 256) {
        const int nn = i / 75, ii = i % 75;
        const size_t idx = (size_t)(nb0 + nn) * 75 + ii;
        snf[nn][ii] = isf32 ? ((const float*)nf_raw)[idx] : bf2f(((const unsigned short*)nf_raw)[idx]);
    }
    __syncthreads();
    const int ln = tid >> 6, d = tid & 63;
    const float bd = b[d];
    #pragma unroll
    for (int g = 0; g < 4; ++g) {
        const int nn = ln * 4 + g;
        float acc = bd;
        #pragma unroll
        for (int i = 0; i < 75; ++i) acc = fmaf(snf[nn][i], sw[i][d], acc);
        out[(size_t)(nb0 + nn) * 64 + d] = fmaxf(acc, 0.0f);
    }
}

// h1 = relu(ef @ w1 + b1) -> bf16 in MFMA FRAGMENT-SEGMENT layout (h1P).
__global__ __launch_bounds__(256) void k1_h1(const void* __restrict__ ef_raw,
                                             const float* __restrict__ w1,
                                             const float* __restrict__ b1,
                                             __hip_bfloat16* __restrict__ h1P,
                                             const int* __restrict__ flag) {
    const int j = threadIdx.x & 127, half = threadIdx.x >> 7;
    const int eb0 = blockIdx.x * 16;
    const int isf32 = *flag;
    __shared__ float efs[16][17];
    {
        const int e = threadIdx.x >> 4, i = threadIdx.x & 15;
        const size_t idx = (size_t)(eb0 + e) * 16 + i;
        efs[e][i] = isf32 ? ((const float*)ef_raw)[idx] : bf2f(((const unsigned short*)ef_raw)[idx]);
    }
    __syncthreads();
    float wcol[16];
    #pragma unroll
    for (int i = 0; i < 16; ++i) wcol[i] = w1[i * 128 + j];
    const float bj = b1[j];
    const int kk = j >> 5, qd = (j >> 3) & 3, jj = j & 7;
    #pragma unroll
    for (int eo = 0; eo < 8; ++eo) {
        const int e = eb0 + half * 8 + eo;
        float acc = bj;
        #pragma unroll
        for (int i = 0; i < 16; ++i) acc = fmaf(efs[half * 8 + eo][i], wcol[i], acc);
        const int ebk = e >> 6, er = e & 63, rb = er >> 4, lre = er & 15;
        h1P[(size_t)ebk * 8192 + (kk * 4 + rb) * 512 + (qd * 16 + lre) * 8 + jj] =
            __float2bfloat16(fmaxf(acc, 0.0f));
    }
}

// FUSED NNConv v13: r11 structure, min-waves 3 -> 4 (116 total regs <= 128
// and 4x33KB LDS <= 160KB both admit a 4th resident block; r11 allocator
// met exactly the hint of 3).
__global__ __launch_bounds__(256, 4) void k23_fused(const __hip_bfloat16* __restrict__ h1P,
                                                 const __hip_bfloat16* __restrict__ w2P,
                                                 const float* __restrict__ b2,
                                                 const float* __restrict__ out,
                                                 const void* __restrict__ eidx,
                                                 const int* __restrict__ fi64,
                                                 float* __restrict__ agg) {
    __shared__ __align__(16) __hip_bfloat16 As[64 * 128];   // 16 KB; aliased as merge buf
    __shared__ float yT[64][65];                            // 16.6 KB [d][e]
    __shared__ int sdx[64];                                 // dst indices
    const int tid = threadIdx.x;
    const int e0 = blockIdx.x * 64;
    const int f64 = *fi64;

    const int wave = tid >> 6, lane = tid & 63;
    const int wn = wave * 32;              // 4 N-slices of 32 cols
    const int lr = lane & 15, quad = lane >> 4;

    if (tid < 64) sdx[tid] = geti(eidx, (long long)GE + e0 + tid, f64);
    // stage As: flat 16KB coalesced copy (h1P is already the LDS image)
    {
        const short8* s8 = (const short8*)(h1P + (size_t)blockIdx.x * 8192);
        short8* d8 = (short8*)As;
        #pragma unroll
        for (int i = 0; i < 4; ++i) d8[i * 256 + tid] = s8[i * 256 + tid];
    }
    // stage yT[d][e] = out[src[e]][d]
    {
        const int e = tid >> 2, d0 = (tid & 3) * 16;
        const int s = geti(eidx, e0 + e, f64);
        const float* srow = out + (size_t)s * 64 + d0;
        #pragma unroll
        for (int j = 0; j < 4; ++j) {
            float4 v = *(const float4*)(srow + j * 4);
            yT[d0 + j * 4 + 0][e] = v.x;
            yT[d0 + j * 4 + 1][e] = v.y;
            yT[d0 + j * 4 + 2][e] = v.z;
            yT[d0 + j * 4 + 3][e] = v.w;
        }
    }
    __syncthreads();

    const int lin = (lr * 4 + quad) * 8;   // lane offset inside a 512-elem group
    const char* Ab = (const char*)As + lane * 16;   // lane-consecutive A base
    float msum[4][2][4] = {};

#define K23_LOADB(dst, tt)                                                      \
    _Pragma("unroll")                                                           \
    for (int kk = 0; kk < 4; ++kk) {                                            \
        _Pragma("unroll")                                                       \
        for (int nt = 0; nt < 2; ++nt) {                                        \
            const int g = ((tt) * 4 + kk) * 8 + (wn >> 4) + nt;                 \
            dst[kk][nt] = *(const short8*)(w2P + (size_t)g * 512 + lin);        \
        }                                                                       \
    }                                                                           \
    __builtin_amdgcn_sched_barrier(0);

#define K23_BODY(tt, buf) {                                                     \
    const int n0 = (tt) * 128;                                                  \
    const int dcur = (n0 + wn) >> 6;                                            \
    const float b2v0 = b2[n0 + wn + lr];                                        \
    const float b2v1 = b2[n0 + wn + 16 + lr];                                   \
    floatx4 acc[4][2] = {};                                                     \
    _Pragma("unroll")                                                           \
    for (int kk = 0; kk < 4; ++kk) {                                            \
        short8 a0, a1, a2, a3;                                                  \
        a0 = *(const short8*)(Ab + kk * 4096 + 0 * 1024);                       \
        a1 = *(const short8*)(Ab + kk * 4096 + 1 * 1024);                       \
        a2 = *(const short8*)(Ab + kk * 4096 + 2 * 1024);                       \
        a3 = *(const short8*)(Ab + kk * 4096 + 3 * 1024);                       \
        __builtin_amdgcn_s_setprio(1);                                          \
        acc[0][0] = __builtin_amdgcn_mfma_f32_16x16x32_bf16(a0, buf[kk][0], acc[0][0], 0, 0, 0); \
        acc[0][1] = __builtin_amdgcn_mfma_f32_16x16x32_bf16(a0, buf[kk][1], acc[0][1], 0, 0, 0); \
        acc[1][0] = __builtin_amdgcn_mfma_f32_16x16x32_bf16(a1, buf[kk][0], acc[1][0], 0, 0, 0); \
        acc[1][1] = __builtin_amdgcn_mfma_f32_16x16x32_bf16(a1, buf[kk][1], acc[1][1], 0, 0, 0); \
        acc[2][0] = __builtin_amdgcn_mfma_f32_16x16x32_bf16(a2, buf[kk][0], acc[2][0], 0, 0, 0); \
        acc[2][1] = __builtin_amdgcn_mfma_f32_16x16x32_bf16(a2, buf[kk][1], acc[2][1], 0, 0, 0); \
        acc[3][0] = __builtin_amdgcn_mfma_f32_16x16x32_bf16(a3, buf[kk][0], acc[3][0], 0, 0, 0); \
        acc[3][1] = __builtin_amdgcn_mfma_f32_16x16x32_bf16(a3, buf[kk][1], acc[3][1], 0, 0, 0); \
        __builtin_amdgcn_s_setprio(0);                                          \
    }                                                                           \
    _Pragma("unroll")                                                           \
    for (int mt = 0; mt < 4; ++mt) {                                            \
        _Pragma("unroll")                                                       \
        for (int r = 0; r < 4; ++r) {                                           \
            const float yv = yT[dcur][mt * 16 + quad * 4 + r];                  \
            msum[mt][0][r] = fmaf(yv, acc[mt][0][r] + b2v0, msum[mt][0][r]);    \
            msum[mt][1][r] = fmaf(yv, acc[mt][1][r] + b2v1, msum[mt][1][r]);    \
        }                                                                       \
    }                                                                           \
}

    short8 bA[4][2], bB[4][2];
    K23_LOADB(bA, 0)
    #pragma unroll 1
    for (int t = 0; t < 32; t += 2) {
        K23_LOADB(bB, t + 1)          // in flight across BODY(t)
        K23_BODY(t, bA)
        if (t + 2 < 32) { K23_LOADB(bA, t + 2) }  // in flight across BODY(t+1)
        K23_BODY(t + 1, bB)
    }
#undef K23_LOADB
#undef K23_BODY

    // merged epilogue: fold wave-pair (wn, wn+64) partials in LDS, then
    // one coalesced atomicAdd set. As (16KB) aliased as 64x64 f32 merge buf.
    __syncthreads();                       // all waves done with As/yT
    float* mg = (float*)As;
    const int fb = (wn & 32);
    if (wave < 2) {
        #pragma unroll
        for (int mt = 0; mt < 4; ++mt)
            #pragma unroll
            for (int r = 0; r < 4; ++r)
                #pragma unroll
                for (int nt = 0; nt < 2; ++nt)
                    mg[(mt * 16 + quad * 4 + r) * 64 + fb + nt * 16 + lr] = msum[mt][nt][r];
    }
    __syncthreads();
    if (wave >= 2) {
        #pragma unroll
        for (int mt = 0; mt < 4; ++mt)
            #pragma unroll
            for (int r = 0; r < 4; ++r)
                #pragma unroll
                for (int nt = 0; nt < 2; ++nt)
                    mg[(mt * 16 + quad * 4 + r) * 64 + fb + nt * 16 + lr] += msum[mt][nt][r];
    }
    __syncthreads();
    #pragma unroll
    for (int i = 0; i < 16; ++i) {
        const int o = i * 256 + tid;
        const int row = o >> 6, col = o & 63;
        atomicAdd(&agg[(size_t)sdx[row] * 64 + col], mg[o]);
    }
}

// GRU v5: MFMA gate GEMMs + in-place agg re-zero; optional dual-write of the
// final h into d_out's feat_map region (kills the k_out copy pass).
__global__ __launch_bounds__(256) void k4_gru(float* __restrict__ agg,
                                              const float* __restrict__ counts,
                                              const float* __restrict__ cbias,
                                              const __hip_bfloat16* __restrict__ gwp,
                                              const float* __restrict__ b_ih,
                                              const float* __restrict__ b_hh,
                                              float* __restrict__ out,
                                              float* __restrict__ dst2) {
    const int wv = threadIdx.x >> 6, lane = threadIdx.x & 63;
    const int lr = lane & 15, quad = lane >> 4;
    const int wnb0 = blockIdx.x * 64 + wv * 16;
    const int node = wnb0 + lr;

    const float rcnt = 1.0f / fmaxf(counts[node], 1.0f);
    float* ap = agg + (size_t)node * 64;
    const float* hp = out + (size_t)node * 64;
    short8 am[2], ah[2];
    #pragma unroll
    for (int kk = 0; kk < 2; ++kk) {
        const int k0 = kk * 32 + quad * 8;
        #pragma unroll
        for (int j = 0; j < 8; ++j) {
            const float mv = fmaxf(ap[k0 + j] * rcnt + cbias[k0 + j], 0.0f);
            const __hip_bfloat16 mb = __float2bfloat16(mv);
            am[kk][j] = *(const short*)&mb;
            const __hip_bfloat16 hb = __float2bfloat16(hp[k0 + j]);
            ah[kk][j] = *(const short*)&hb;
        }
    }
    // zero agg for the next NNConv iteration (replaces memset dispatch)
    {
        const float4 z = {0.0f, 0.0f, 0.0f, 0.0f};
        #pragma unroll
        for (int kk = 0; kk < 2; ++kk) {
            const int k0 = kk * 32 + quad * 8;
            *(float4*)(ap + k0) = z;
            *(float4*)(ap + k0 + 4) = z;
        }
    }

    floatx4 ai[12] = {}, ahh[12] = {};
    #pragma unroll
    for (int nb = 0; nb < 12; ++nb) {
        #pragma unroll
        for (int kk = 0; kk < 2; ++kk) {
            #pragma unroll
            for (int part = 0; part < 2; ++part) {
                const short8 bi = *(const short8*)(gwp + (size_t)(((0 * 12 + nb) * 2 + kk) * 2 + part) * 512 + lane * 8);
                ai[nb] = __builtin_amdgcn_mfma_f32_16x16x32_bf16(am[kk], bi, ai[nb], 0, 0, 0);
                const short8 bh = *(const short8*)(gwp + (size_t)(((1 * 12 + nb) * 2 + kk) * 2 + part) * 512 + lane * 8);
                ahh[nb] = __builtin_amdgcn_mfma_f32_16x16x32_bf16(ah[kk], bh, ahh[nb], 0, 0, 0);
            }
        }
    }

    #pragma unroll
    for (int f = 0; f < 4; ++f) {
        const int d = f * 16 + lr;
        const float bir = b_ih[d],       bhr = b_hh[d];
        const float biz = b_ih[64 + d],  bhz = b_hh[64 + d];
        const float bin = b_ih[128 + d], bhn = b_hh[128 + d];
        #pragma unroll
        for (int r = 0; r < 4; ++r) {
            const int row = wnb0 + quad * 4 + r;
            const float rr = sigm(ai[f][r] + bir + ahh[f][r] + bhr);
            const float zz = sigm(ai[f + 4][r] + biz + ahh[f + 4][r] + bhz);
            const float nn = tanhf(ai[f + 8][r] + bin + rr * (ahh[f + 8][r] + bhn));
            const float hd = out[(size_t)row * 64 + d];
            const float hnew = (1.0f - zz) * nn + zz * hd;
            out[(size_t)row * 64 + d] = hnew;
            if (dst2) dst2[(size_t)row * 64 + d] = hnew;
        }
    }
}

// FUSED Set2Set: all 3 processing steps in ONE launch; writes q* directly to dstq.
__global__ __launch_bounds__(256) void k5_fused(float* __restrict__ dstq,
                                                const float* __restrict__ w_ih,
                                                const float* __restrict__ w_hh,
                                                const float* __restrict__ b_ih,
                                                const float* __restrict__ b_hh,
                                                const float* __restrict__ out,
                                                const int* __restrict__ rowptr) {
    const int g = blockIdx.x;
    const int j = threadIdx.x;
    __shared__ float qs[128], hv[64], gates[256];
    __shared__ float smw[4], sSw[4], srw[4][64];
    if (j < 128) qs[j] = 0.0f;
    if (j < 64) hv[j] = 0.0f;
    float creg = 0.0f;               // cs state (threads j<64)
    const int wv = j >> 6, lane = j & 63;
    const int start = rowptr[g], end = rowptr[g + 1];
    const float bsum = b_ih[j] + b_hh[j];

    for (int step = 0; step < 3; ++step) {
        __syncthreads();             // qs/hv (and smw/srw reuse) ready
        float acc = bsum;
        for (int k4 = 0; k4 < 128; k4 += 4) {
            float4 v = *(const float4*)(w_ih + (size_t)j * 128 + k4);
            const float* pv = (const float*)&v;
            #pragma unroll
            for (int t = 0; t < 4; ++t) acc += qs[k4 + t] * pv[t];
        }
        for (int k4 = 0; k4 < 64; k4 += 4) {
            float4 v = *(const float4*)(w_hh + (size_t)j * 64 + k4);
            const float* pv = (const float*)&v;
            #pragma unroll
            for (int t = 0; t < 4; ++t) acc += hv[k4 + t] * pv[t];
        }
        gates[j] = acc;
        __syncthreads();
        if (j < 64) {
            const float ig = sigm(gates[j]);
            const float fg = sigm(gates[64 + j]);
            const float gg = tanhf(gates[128 + j]);
            const float og = sigm(gates[192 + j]);
            creg = fg * creg + ig * gg;
            const float h = og * tanhf(creg);
            hv[j] = h;
            qs[j] = h;
        }
        __syncthreads();
        // attention: wave wv handles nodes start+wv, start+wv+4, ...
        const float q = hv[lane];
        float m = -3.4e38f, S = 0.0f, racc = 0.0f;
        for (int n = start + wv; n < end; n += 4) {
            const float ov = out[(size_t)n * 64 + lane];
            float p = ov * q;
            #pragma unroll
            for (int off = 1; off < 64; off <<= 1) p += __shfl_xor(p, off);
            if (p > m) {
                const float sc = __expf(m - p);
                S = S * sc + 1.0f;
                racc = racc * sc + ov;
                m = p;
            } else {
                const float w = __expf(p - m);
                S += w;
                racc += w * ov;
            }
        }
        if (lane == 0) { smw[wv] = m; sSw[wv] = S; }
        srw[wv][lane] = racc;
        __syncthreads();
        if (wv == 0) {
            const float mstar = fmaxf(fmaxf(smw[0], smw[1]), fmaxf(smw[2], smw[3]));
            float Ssum = 0.0f, rsum = 0.0f;
            #pragma unroll
            for (int i = 0; i < 4; ++i) {
                const float sc = __expf(smw[i] - mstar);   // empty wave: exp(-huge)=0
                Ssum += sSw[i] * sc;
                rsum += srw[i][lane] * sc;
            }
            qs[64 + lane] = rsum / (Ssum + 1e-16f);
        }
    }
    __syncthreads();
    if (j < 128) dstq[(size_t)g * 128 + j] = qs[j];
}

__global__ void k_out(const float* __restrict__ qstar, const float* __restrict__ outb,
                      float* __restrict__ dst, int nq, int nfeat, int out_n) {
    int i = blockIdx.x * 256 + threadIdx.x;
    if (i >= out_n) return;
    float v = 0.0f;
    if (i < nq) v = qstar[i];
    else if (i - nq < nfeat) v = outb[i - nq];
    dst[i] = v;
}

extern "C" void kernel_launch(void* const* d_in, const int* in_sizes, int n_in,
                              void* d_out, int out_size, void* d_ws, size_t ws_size,
                              hipStream_t stream) {
    constexpr int N = GN, E = GE, B = GB;

    char* ws = (char*)d_ws;
    size_t off = 0;
    auto alloc = [&](size_t bytes) { size_t o = off; off = (off + bytes + 255) & ~(size_t)255; return o; };

    int*   fl     = (int*)  (ws + alloc(19 * 4));
    int*   flagE  = (int*)  (ws + alloc(256));
    int*   flagG  = (int*)  (ws + alloc(256));
    float* counts = (float*)(ws + alloc((size_t)N * 4));
    int*   rowptr = (int*)  (ws + alloc((size_t)(B + 1) * 4));
    float* outbuf = (float*)(ws + alloc((size_t)N * 64 * 4));
    float* agg    = (float*)(ws + alloc((size_t)N * 64 * 4));
    float* qstar  = (float*)(ws + alloc((size_t)B * 128 * 4));
    __hip_bfloat16* h1P = (__hip_bfloat16*)(ws + alloc((size_t)E * 128 * 2));
    __hip_bfloat16* w2P = (__hip_bfloat16*)(ws + alloc((size_t)4096 * 128 * 2));
    __hip_bfloat16* gwp = (__hip_bfloat16*)(ws + alloc((size_t)2 * 12 * 2 * 2 * 512 * 2));

    const int fidx[15]  = {4, 5, 6, 7, 8, 9, 10, 11, 12, 13, 14, 15, 16, 17, 18};
    const int fsize[15] = {75 * 64, 64, 16 * 128, 128, 128 * 4096, 4096, 64,
                           192 * 64, 192 * 64, 192, 192, 256 * 128, 256 * 64, 256, 256};
    float* F[19] = {};
    for (int t = 0; t < 15; ++t) F[fidx[t]] = (float*)(ws + alloc((size_t)fsize[t] * 4));

    DetectArgs da;
    da.src[0] = d_in[0]; da.nhalf[0] = N * 75; da.fi[0] = 0;
    da.src[1] = d_in[1]; da.nhalf[1] = E * 16; da.fi[1] = 1;
    for (int t = 0; t < 15; ++t) { da.src[2 + t] = d_in[fidx[t]]; da.nhalf[2 + t] = fsize[t]; da.fi[2 + t] = fidx[t]; }
    k_detect<<<19, 256, 0, stream>>>(da, (const unsigned int*)d_in[2],
                                     (const unsigned int*)d_in[3], fl, flagE, flagG);

    // cvt list: 14 tensors (w2 -> F[8] dropped; consumed via k_t2 directly)
    const int cidx[14]  = {4, 5, 6, 7, 9, 10, 11, 12, 13, 14, 15, 16, 17, 18};
    const int csize[14] = {75 * 64, 64, 16 * 128, 128, 4096, 64,
                           192 * 64, 192 * 64, 192, 192, 256 * 128, 256 * 64, 256, 256};
    CvtArgs ca;
    int pre = 0;
    for (int t = 0; t < 14; ++t) {
        ca.src[t] = d_in[cidx[t]]; ca.dst[t] = F[cidx[t]]; ca.n[t] = csize[t]; ca.fi[t] = cidx[t];
        ca.pre[t] = pre; pre += (csize[t] + 255) / 256;
    }
    ca.src[14] = d_in[4]; ca.dst[14] = F[4]; ca.n[14] = 0; ca.fi[14] = 4;
    ca.pre[14] = pre; ca.pre[15] = pre;
    k_cvt_all<<<pre, 256, 0, stream>>>(ca, fl);
    k_t2<<<256, 256, 0, stream>>>(d_in[8], w2P, fl + 8);
    k_gpack2<<<12, 256, 0, stream>>>(F[11], F[12], gwp);

    hipMemsetAsync(counts, 0, (size_t)N * 4, stream);
    hipMemsetAsync(agg, 0, (size_t)N * 64 * 4, stream);

    // direct-output mode: write q* and feat_map straight into d_out
    const long long need = (long long)B * 128 + (long long)N * 64;
    const bool direct = (long long)out_size >= need;
    if (direct && (long long)out_size > need)
        hipMemsetAsync((float*)d_out + need, 0, ((size_t)out_size - (size_t)need) * 4, stream);
    if (!direct) hipMemsetAsync(qstar, 0, (size_t)B * 128 * 4, stream);

    k_cnt_rp<<<512 + (B + 1 + 255) / 256, 256, 0, stream>>>(d_in[2], d_in[3], flagE, flagG,
                                                            counts, rowptr);
    k_lin0<<<N / 16, 256, 0, stream>>>(d_in[0], F[4], F[5], outbuf, fl + 0);
    k1_h1<<<E / 16, 256, 0, stream>>>(d_in[1], F[6], F[7], h1P, fl + 1);

    for (int it = 0; it < 3; ++it) {
        k23_fused<<<E / 64, 256, 0, stream>>>(h1P, w2P, F[9], outbuf, d_in[2], flagE, agg);
        float* dst2 = (direct && it == 2) ? ((float*)d_out + (size_t)B * 128) : nullptr;
        k4_gru<<<N / 64, 256, 0, stream>>>(agg, counts, F[10], gwp, F[13], F[14], outbuf, dst2);
    }
    float* dstq = direct ? (float*)d_out : qstar;
    k5_fused<<<B, 256, 0, stream>>>(dstq, F[15], F[16], F[17], F[18], outbuf, rowptr);
    if (!direct)
        k_out<<<(out_size + 255) / 256, 256, 0, stream>>>(qstar, outbuf, (float*)d_out,
                                                          B * 128, N * 64, out_size);
}

// Round 13
// 880.501 us; speedup vs baseline: 1.9571x; 1.9571x over previous
//
#include <hip/hip_runtime.h>
#include <hip/hip_bf16.h>

#define GN 65536
#define GE 131072
#define GB 2048

typedef __attribute__((ext_vector_type(8))) short short8;
typedef __attribute__((ext_vector_type(4))) float floatx4;

static __device__ __forceinline__ float sigm(float x) { return 1.0f / (1.0f + __expf(-x)); }
static __device__ __forceinline__ float bf2f(unsigned short u) {
    union { unsigned int i; float f; } v; v.i = ((unsigned int)u) << 16; return v.f;
}
static __device__ __forceinline__ int geti(const void* p, long long i, int f64) {
    return f64 ? (int)((const long long*)p)[i] : ((const int*)p)[i];
}

// ---- merged detectors: blocks 0-16 float-dtype, 17 edge-i64, 18 graph-i64 ----
struct DetectArgs { const void* src[17]; int nhalf[17]; int fi[17]; };
__global__ void k_detect(DetectArgs a, const unsigned int* __restrict__ pe,
                         const unsigned int* __restrict__ pg,
                         int* __restrict__ flags, int* __restrict__ flagE,
                         int* __restrict__ flagG) {
    __shared__ unsigned int sA[256], sB[256];
    if (blockIdx.x >= 17) {
        const unsigned int* p = (blockIdx.x == 17) ? pe : pg;
        const long long nwords = (blockIdx.x == 17) ? (long long)2 * GE : (long long)GN;
        const long long lim = nwords < 16384 ? nwords : 16384;
        unsigned int acc = 0;
        for (long long w = 1 + 2 * (long long)threadIdx.x; w < lim; w += 512) acc |= p[w];
        sA[threadIdx.x] = acc;
        __syncthreads();
        for (int st = 128; st > 0; st >>= 1) {
            if (threadIdx.x < st) sA[threadIdx.x] |= sA[threadIdx.x + st];
            __syncthreads();
        }
        if (threadIdx.x == 0) *((blockIdx.x == 17) ? flagE : flagG) = (sA[0] == 0u) ? 1 : 0;
        return;
    }
    const unsigned short* p = (const unsigned short*)a.src[blockIdx.x];
    const int n0 = a.nhalf[blockIdx.x];
    const int n = n0 < 16384 ? n0 : 16384;
    unsigned int any = 0, orEven = 0;
    for (int i = threadIdx.x; i < n; i += 256) {
        const unsigned short u = p[i];
        const float av = fabsf(bf2f(u));
        if (!(av <= 1e6f)) any = 1u;
        if ((i & 1) == 0) orEven |= u;
    }
    sA[threadIdx.x] = any; sB[threadIdx.x] = orEven;
    __syncthreads();
    for (int s = 128; s > 0; s >>= 1) {
        if (threadIdx.x < s) {
            sA[threadIdx.x] |= sA[threadIdx.x + s];
            sB[threadIdx.x] |= sB[threadIdx.x + s];
        }
        __syncthreads();
    }
    if (threadIdx.x == 0) flags[a.fi[blockIdx.x]] = (sA[0] || sB[0] == 0u) ? 1 : 0;
}

// ---- batched f32 canonicalization (14 tensors; dead w2->F[8] conversion dropped) ----
struct CvtArgs { const void* src[15]; float* dst[15]; int n[15]; int fi[15]; int pre[16]; };
__global__ void k_cvt_all(CvtArgs a, const int* __restrict__ flags) {
    const int b = blockIdx.x;
    int t = 0;
    while (t < 14 && b >= a.pre[t + 1]) ++t;
    const int i = (b - a.pre[t]) * 256 + threadIdx.x;
    if (i >= a.n[t]) return;
    const int f = flags[a.fi[t]];
    a.dst[t][i] = f ? ((const float*)a.src[t])[i] : bf2f(((const unsigned short*)a.src[t])[i]);
}

// repack w2 [128][4096] -> w2P bf16, COALESCED-FRAGMENT layout:
// group g = ((t*4 + kk)*8 + rb); each wave fragment load is one contiguous 1KB segment.
__global__ __launch_bounds__(256) void k_t2(const void* __restrict__ src,
                                            __hip_bfloat16* __restrict__ w2P,
                                            const int* __restrict__ flag) {
    const int tid8 = blockIdx.x * 256 + threadIdx.x;   // 65536 producers of 8 elems
    const int quad = tid8 & 3, lr = (tid8 >> 2) & 15, rb = (tid8 >> 6) & 7,
              kk = (tid8 >> 9) & 3, t = tid8 >> 11;
    const int n = t * 128 + rb * 16 + lr;              // output col 0..4095
    const int k0 = kk * 32 + quad * 8;                 // k 0..127
    const int isf32 = *flag;
    short8 v;
    #pragma unroll
    for (int j = 0; j < 8; ++j) {
        const size_t si = (size_t)(k0 + j) * 4096 + n;
        const float f = isf32 ? ((const float*)src)[si] : bf2f(((const unsigned short*)src)[si]);
        const __hip_bfloat16 b = __float2bfloat16(f);
        v[j] = *(const short*)&b;
    }
    *(short8*)(w2P + (size_t)tid8 * 8) = v;
}

// pack GRU weights into MFMA B-fragment layout, hi/lo bf16 split.
__global__ void k_gpack2(const float* __restrict__ w_ih, const float* __restrict__ w_hh,
                         __hip_bfloat16* __restrict__ gwp) {
    const int t = blockIdx.x * 256 + threadIdx.x;
    if (t >= 3072) return;
    const int lane = t & 63;
    const int kk = (t >> 6) & 1;
    const int nb = (t >> 7) % 12;
    const int mat = t / 1536;
    const float* W = mat ? w_hh : w_ih;          // [192][64]
    const int c = nb * 16 + (lane & 15);
    const int k0 = kk * 32 + (lane >> 4) * 8;
    short8 hi, lo;
    #pragma unroll
    for (int j = 0; j < 8; ++j) {
        const float v = W[c * 64 + k0 + j];
        const __hip_bfloat16 bh = __float2bfloat16(v);
        hi[j] = *(const short*)&bh;
        const __hip_bfloat16 bl = __float2bfloat16(v - __bfloat162float(bh));
        lo[j] = *(const short*)&bl;
    }
    const size_t base = (size_t)(((mat * 12 + nb) * 2 + kk) * 2);
    *(short8*)(gwp + (base + 0) * 512 + lane * 8) = hi;
    *(short8*)(gwp + (base + 1) * 512 + lane * 8) = lo;
}

// merged: blocks 0..511 = edge-count atomics; blocks 512+ = rowptr binary search
__global__ void k_cnt_rp(const void* __restrict__ eidx, const void* __restrict__ gi,
                         const int* __restrict__ flagE, const int* __restrict__ flagG,
                         float* __restrict__ counts, int* __restrict__ rowptr) {
    if (blockIdx.x < 512) {
        const int e = blockIdx.x * 256 + threadIdx.x;
        atomicAdd(&counts[geti(eidx, (long long)GE + e, *flagE)], 1.0f);
        return;
    }
    const int g = (blockIdx.x - 512) * 256 + threadIdx.x;
    if (g > GB) return;
    const int f64 = *flagG;
    int lo = 0, hi = GN;
    while (lo < hi) { int mid = (lo + hi) >> 1; if (geti(gi, mid, f64) < g) lo = mid + 1; else hi = mid; }
    rowptr[g] = lo;
}

// lin0: out = relu(nf @ lin0_w + b); 16 nodes/block, whole w staged in LDS
__global__ __launch_bounds__(256) void k_lin0(const void* __restrict__ nf_raw,
                                              const float* __restrict__ w,
                                              const float* __restrict__ b,
                                              float* __restrict__ out,
                                              const int* __restrict__ flag) {
    __shared__ float sw[75][66];
    __shared__ float snf[16][76];
    const int tid = threadIdx.x;
    const int isf32 = *flag;
    const int nb0 = blockIdx.x * 16;
    for (int i = tid; i < 75 * 64; i += 256) sw[i >> 6][i & 63] = w[i];
    for (int i = tid; i < 16 * 75; i += 256) {
        const int nn = i / 75, ii = i % 75;
        const size_t idx = (size_t)(nb0 + nn) * 75 + ii;
        snf[nn][ii] = isf32 ? ((const float*)nf_raw)[idx] : bf2f(((const unsigned short*)nf_raw)[idx]);
    }
    __syncthreads();
    const int ln = tid >> 6, d = tid & 63;
    const float bd = b[d];
    #pragma unroll
    for (int g = 0; g < 4; ++g) {
        const int nn = ln * 4 + g;
        float acc = bd;
        #pragma unroll
        for (int i = 0; i < 75; ++i) acc = fmaf(snf[nn][i], sw[i][d], acc);
        out[(size_t)(nb0 + nn) * 64 + d] = fmaxf(acc, 0.0f);
    }
}

// h1 = relu(ef @ w1 + b1) -> bf16 in MFMA FRAGMENT-SEGMENT layout (h1P).
__global__ __launch_bounds__(256) void k1_h1(const void* __restrict__ ef_raw,
                                             const float* __restrict__ w1,
                                             const float* __restrict__ b1,
                                             __hip_bfloat16* __restrict__ h1P,
                                             const int* __restrict__ flag) {
    const int j = threadIdx.x & 127, half = threadIdx.x >> 7;
    const int eb0 = blockIdx.x * 16;
    const int isf32 = *flag;
    __shared__ float efs[16][17];
    {
        const int e = threadIdx.x >> 4, i = threadIdx.x & 15;
        const size_t idx = (size_t)(eb0 + e) * 16 + i;
        efs[e][i] = isf32 ? ((const float*)ef_raw)[idx] : bf2f(((const unsigned short*)ef_raw)[idx]);
    }
    __syncthreads();
    float wcol[16];
    #pragma unroll
    for (int i = 0; i < 16; ++i) wcol[i] = w1[i * 128 + j];
    const float bj = b1[j];
    const int kk = j >> 5, qd = (j >> 3) & 3, jj = j & 7;
    #pragma unroll
    for (int eo = 0; eo < 8; ++eo) {
        const int e = eb0 + half * 8 + eo;
        float acc = bj;
        #pragma unroll
        for (int i = 0; i < 16; ++i) acc = fmaf(efs[half * 8 + eo][i], wcol[i], acc);
        const int ebk = e >> 6, er = e & 63, rb = er >> 4, lre = er & 15;
        h1P[(size_t)ebk * 8192 + (kk * 4 + rb) * 512 + (qd * 16 + lre) * 8 + jj] =
            __float2bfloat16(fmaxf(acc, 0.0f));
    }
}

// FUSED NNConv v13b: r11's verified best (min-waves 3; VGPR 84, Occ 30%,
// 161.6us). r12's min-waves=4 forced VGPR->64 and SPILLED the B dbuf to
// scratch (FETCH 36.7->742MB, WRITE 32.8MB->1.37GB) -- 3 is the max for
// this register footprint (84 arch + 32 AGPR + msum in VGPRs ~ 148/thread).
__global__ __launch_bounds__(256, 3) void k23_fused(const __hip_bfloat16* __restrict__ h1P,
                                                 const __hip_bfloat16* __restrict__ w2P,
                                                 const float* __restrict__ b2,
                                                 const float* __restrict__ out,
                                                 const void* __restrict__ eidx,
                                                 const int* __restrict__ fi64,
                                                 float* __restrict__ agg) {
    __shared__ __align__(16) __hip_bfloat16 As[64 * 128];   // 16 KB; aliased as merge buf
    __shared__ float yT[64][65];                            // 16.6 KB [d][e]
    __shared__ int sdx[64];                                 // dst indices
    const int tid = threadIdx.x;
    const int e0 = blockIdx.x * 64;
    const int f64 = *fi64;

    const int wave = tid >> 6, lane = tid & 63;
    const int wn = wave * 32;              // 4 N-slices of 32 cols
    const int lr = lane & 15, quad = lane >> 4;

    if (tid < 64) sdx[tid] = geti(eidx, (long long)GE + e0 + tid, f64);
    // stage As: flat 16KB coalesced copy (h1P is already the LDS image)
    {
        const short8* s8 = (const short8*)(h1P + (size_t)blockIdx.x * 8192);
        short8* d8 = (short8*)As;
        #pragma unroll
        for (int i = 0; i < 4; ++i) d8[i * 256 + tid] = s8[i * 256 + tid];
    }
    // stage yT[d][e] = out[src[e]][d]
    {
        const int e = tid >> 2, d0 = (tid & 3) * 16;
        const int s = geti(eidx, e0 + e, f64);
        const float* srow = out + (size_t)s * 64 + d0;
        #pragma unroll
        for (int j = 0; j < 4; ++j) {
            float4 v = *(const float4*)(srow + j * 4);
            yT[d0 + j * 4 + 0][e] = v.x;
            yT[d0 + j * 4 + 1][e] = v.y;
            yT[d0 + j * 4 + 2][e] = v.z;
            yT[d0 + j * 4 + 3][e] = v.w;
        }
    }
    __syncthreads();

    const int lin = (lr * 4 + quad) * 8;   // lane offset inside a 512-elem group
    const char* Ab = (const char*)As + lane * 16;   // lane-consecutive A base
    float msum[4][2][4] = {};

#define K23_LOADB(dst, tt)                                                      \
    _Pragma("unroll")                                                           \
    for (int kk = 0; kk < 4; ++kk) {                                            \
        _Pragma("unroll")                                                       \
        for (int nt = 0; nt < 2; ++nt) {                                        \
            const int g = ((tt) * 4 + kk) * 8 + (wn >> 4) + nt;                 \
            dst[kk][nt] = *(const short8*)(w2P + (size_t)g * 512 + lin);        \
        }                                                                       \
    }                                                                           \
    __builtin_amdgcn_sched_barrier(0);

#define K23_BODY(tt, buf) {                                                     \
    const int n0 = (tt) * 128;                                                  \
    const int dcur = (n0 + wn) >> 6;                                            \
    const float b2v0 = b2[n0 + wn + lr];                                        \
    const float b2v1 = b2[n0 + wn + 16 + lr];                                   \
    floatx4 acc[4][2] = {};                                                     \
    _Pragma("unroll")                                                           \
    for (int kk = 0; kk < 4; ++kk) {                                            \
        short8 a0, a1, a2, a3;                                                  \
        a0 = *(const short8*)(Ab + kk * 4096 + 0 * 1024);                       \
        a1 = *(const short8*)(Ab + kk * 4096 + 1 * 1024);                       \
        a2 = *(const short8*)(Ab + kk * 4096 + 2 * 1024);                       \
        a3 = *(const short8*)(Ab + kk * 4096 + 3 * 1024);                       \
        __builtin_amdgcn_s_setprio(1);                                          \
        acc[0][0] = __builtin_amdgcn_mfma_f32_16x16x32_bf16(a0, buf[kk][0], acc[0][0], 0, 0, 0); \
        acc[0][1] = __builtin_amdgcn_mfma_f32_16x16x32_bf16(a0, buf[kk][1], acc[0][1], 0, 0, 0); \
        acc[1][0] = __builtin_amdgcn_mfma_f32_16x16x32_bf16(a1, buf[kk][0], acc[1][0], 0, 0, 0); \
        acc[1][1] = __builtin_amdgcn_mfma_f32_16x16x32_bf16(a1, buf[kk][1], acc[1][1], 0, 0, 0); \
        acc[2][0] = __builtin_amdgcn_mfma_f32_16x16x32_bf16(a2, buf[kk][0], acc[2][0], 0, 0, 0); \
        acc[2][1] = __builtin_amdgcn_mfma_f32_16x16x32_bf16(a2, buf[kk][1], acc[2][1], 0, 0, 0); \
        acc[3][0] = __builtin_amdgcn_mfma_f32_16x16x32_bf16(a3, buf[kk][0], acc[3][0], 0, 0, 0); \
        acc[3][1] = __builtin_amdgcn_mfma_f32_16x16x32_bf16(a3, buf[kk][1], acc[3][1], 0, 0, 0); \
        __builtin_amdgcn_s_setprio(0);                                          \
    }                                                                           \
    _Pragma("unroll")                                                           \
    for (int mt = 0; mt < 4; ++mt) {                                            \
        _Pragma("unroll")                                                       \
        for (int r = 0; r < 4; ++r) {                                           \
            const float yv = yT[dcur][mt * 16 + quad * 4 + r];                  \
            msum[mt][0][r] = fmaf(yv, acc[mt][0][r] + b2v0, msum[mt][0][r]);    \
            msum[mt][1][r] = fmaf(yv, acc[mt][1][r] + b2v1, msum[mt][1][r]);    \
        }                                                                       \
    }                                                                           \
}

    short8 bA[4][2], bB[4][2];
    K23_LOADB(bA, 0)
    #pragma unroll 1
    for (int t = 0; t < 32; t += 2) {
        K23_LOADB(bB, t + 1)          // in flight across BODY(t)
        K23_BODY(t, bA)
        if (t + 2 < 32) { K23_LOADB(bA, t + 2) }  // in flight across BODY(t+1)
        K23_BODY(t + 1, bB)
    }
#undef K23_LOADB
#undef K23_BODY

    // merged epilogue: fold wave-pair (wn, wn+64) partials in LDS, then
    // one coalesced atomicAdd set. As (16KB) aliased as 64x64 f32 merge buf.
    __syncthreads();                       // all waves done with As/yT
    float* mg = (float*)As;
    const int fb = (wn & 32);
    if (wave < 2) {
        #pragma unroll
        for (int mt = 0; mt < 4; ++mt)
            #pragma unroll
            for (int r = 0; r < 4; ++r)
                #pragma unroll
                for (int nt = 0; nt < 2; ++nt)
                    mg[(mt * 16 + quad * 4 + r) * 64 + fb + nt * 16 + lr] = msum[mt][nt][r];
    }
    __syncthreads();
    if (wave >= 2) {
        #pragma unroll
        for (int mt = 0; mt < 4; ++mt)
            #pragma unroll
            for (int r = 0; r < 4; ++r)
                #pragma unroll
                for (int nt = 0; nt < 2; ++nt)
                    mg[(mt * 16 + quad * 4 + r) * 64 + fb + nt * 16 + lr] += msum[mt][nt][r];
    }
    __syncthreads();
    #pragma unroll
    for (int i = 0; i < 16; ++i) {
        const int o = i * 256 + tid;
        const int row = o >> 6, col = o & 63;
        atomicAdd(&agg[(size_t)sdx[row] * 64 + col], mg[o]);
    }
}

// GRU v5: MFMA gate GEMMs + in-place agg re-zero; optional dual-write of the
// final h into d_out's feat_map region (kills the k_out copy pass).
__global__ __launch_bounds__(256) void k4_gru(float* __restrict__ agg,
                                              const float* __restrict__ counts,
                                              const float* __restrict__ cbias,
                                              const __hip_bfloat16* __restrict__ gwp,
                                              const float* __restrict__ b_ih,
                                              const float* __restrict__ b_hh,
                                              float* __restrict__ out,
                                              float* __restrict__ dst2) {
    const int wv = threadIdx.x >> 6, lane = threadIdx.x & 63;
    const int lr = lane & 15, quad = lane >> 4;
    const int wnb0 = blockIdx.x * 64 + wv * 16;
    const int node = wnb0 + lr;

    const float rcnt = 1.0f / fmaxf(counts[node], 1.0f);
    float* ap = agg + (size_t)node * 64;
    const float* hp = out + (size_t)node * 64;
    short8 am[2], ah[2];
    #pragma unroll
    for (int kk = 0; kk < 2; ++kk) {
        const int k0 = kk * 32 + quad * 8;
        #pragma unroll
        for (int j = 0; j < 8; ++j) {
            const float mv = fmaxf(ap[k0 + j] * rcnt + cbias[k0 + j], 0.0f);
            const __hip_bfloat16 mb = __float2bfloat16(mv);
            am[kk][j] = *(const short*)&mb;
            const __hip_bfloat16 hb = __float2bfloat16(hp[k0 + j]);
            ah[kk][j] = *(const short*)&hb;
        }
    }
    // zero agg for the next NNConv iteration (replaces memset dispatch)
    {
        const float4 z = {0.0f, 0.0f, 0.0f, 0.0f};
        #pragma unroll
        for (int kk = 0; kk < 2; ++kk) {
            const int k0 = kk * 32 + quad * 8;
            *(float4*)(ap + k0) = z;
            *(float4*)(ap + k0 + 4) = z;
        }
    }

    floatx4 ai[12] = {}, ahh[12] = {};
    #pragma unroll
    for (int nb = 0; nb < 12; ++nb) {
        #pragma unroll
        for (int kk = 0; kk < 2; ++kk) {
            #pragma unroll
            for (int part = 0; part < 2; ++part) {
                const short8 bi = *(const short8*)(gwp + (size_t)(((0 * 12 + nb) * 2 + kk) * 2 + part) * 512 + lane * 8);
                ai[nb] = __builtin_amdgcn_mfma_f32_16x16x32_bf16(am[kk], bi, ai[nb], 0, 0, 0);
                const short8 bh = *(const short8*)(gwp + (size_t)(((1 * 12 + nb) * 2 + kk) * 2 + part) * 512 + lane * 8);
                ahh[nb] = __builtin_amdgcn_mfma_f32_16x16x32_bf16(ah[kk], bh, ahh[nb], 0, 0, 0);
            }
        }
    }

    #pragma unroll
    for (int f = 0; f < 4; ++f) {
        const int d = f * 16 + lr;
        const float bir = b_ih[d],       bhr = b_hh[d];
        const float biz = b_ih[64 + d],  bhz = b_hh[64 + d];
        const float bin = b_ih[128 + d], bhn = b_hh[128 + d];
        #pragma unroll
        for (int r = 0; r < 4; ++r) {
            const int row = wnb0 + quad * 4 + r;
            const float rr = sigm(ai[f][r] + bir + ahh[f][r] + bhr);
            const float zz = sigm(ai[f + 4][r] + biz + ahh[f + 4][r] + bhz);
            const float nn = tanhf(ai[f + 8][r] + bin + rr * (ahh[f + 8][r] + bhn));
            const float hd = out[(size_t)row * 64 + d];
            const float hnew = (1.0f - zz) * nn + zz * hd;
            out[(size_t)row * 64 + d] = hnew;
            if (dst2) dst2[(size_t)row * 64 + d] = hnew;
        }
    }
}

// FUSED Set2Set: all 3 processing steps in ONE launch; writes q* directly to dstq.
__global__ __launch_bounds__(256) void k5_fused(float* __restrict__ dstq,
                                                const float* __restrict__ w_ih,
                                                const float* __restrict__ w_hh,
                                                const float* __restrict__ b_ih,
                                                const float* __restrict__ b_hh,
                                                const float* __restrict__ out,
                                                const int* __restrict__ rowptr) {
    const int g = blockIdx.x;
    const int j = threadIdx.x;
    __shared__ float qs[128], hv[64], gates[256];
    __shared__ float smw[4], sSw[4], srw[4][64];
    if (j < 128) qs[j] = 0.0f;
    if (j < 64) hv[j] = 0.0f;
    float creg = 0.0f;               // cs state (threads j<64)
    const int wv = j >> 6, lane = j & 63;
    const int start = rowptr[g], end = rowptr[g + 1];
    const float bsum = b_ih[j] + b_hh[j];

    for (int step = 0; step < 3; ++step) {
        __syncthreads();             // qs/hv (and smw/srw reuse) ready
        float acc = bsum;
        for (int k4 = 0; k4 < 128; k4 += 4) {
            float4 v = *(const float4*)(w_ih + (size_t)j * 128 + k4);
            const float* pv = (const float*)&v;
            #pragma unroll
            for (int t = 0; t < 4; ++t) acc += qs[k4 + t] * pv[t];
        }
        for (int k4 = 0; k4 < 64; k4 += 4) {
            float4 v = *(const float4*)(w_hh + (size_t)j * 64 + k4);
            const float* pv = (const float*)&v;
            #pragma unroll
            for (int t = 0; t < 4; ++t) acc += hv[k4 + t] * pv[t];
        }
        gates[j] = acc;
        __syncthreads();
        if (j < 64) {
            const float ig = sigm(gates[j]);
            const float fg = sigm(gates[64 + j]);
            const float gg = tanhf(gates[128 + j]);
            const float og = sigm(gates[192 + j]);
            creg = fg * creg + ig * gg;
            const float h = og * tanhf(creg);
            hv[j] = h;
            qs[j] = h;
        }
        __syncthreads();
        // attention: wave wv handles nodes start+wv, start+wv+4, ...
        const float q = hv[lane];
        float m = -3.4e38f, S = 0.0f, racc = 0.0f;
        for (int n = start + wv; n < end; n += 4) {
            const float ov = out[(size_t)n * 64 + lane];
            float p = ov * q;
            #pragma unroll
            for (int off = 1; off < 64; off <<= 1) p += __shfl_xor(p, off);
            if (p > m) {
                const float sc = __expf(m - p);
                S = S * sc + 1.0f;
                racc = racc * sc + ov;
                m = p;
            } else {
                const float w = __expf(p - m);
                S += w;
                racc += w * ov;
            }
        }
        if (lane == 0) { smw[wv] = m; sSw[wv] = S; }
        srw[wv][lane] = racc;
        __syncthreads();
        if (wv == 0) {
            const float mstar = fmaxf(fmaxf(smw[0], smw[1]), fmaxf(smw[2], smw[3]));
            float Ssum = 0.0f, rsum = 0.0f;
            #pragma unroll
            for (int i = 0; i < 4; ++i) {
                const float sc = __expf(smw[i] - mstar);   // empty wave: exp(-huge)=0
                Ssum += sSw[i] * sc;
                rsum += srw[i][lane] * sc;
            }
            qs[64 + lane] = rsum / (Ssum + 1e-16f);
        }
    }
    __syncthreads();
    if (j < 128) dstq[(size_t)g * 128 + j] = qs[j];
}

__global__ void k_out(const float* __restrict__ qstar, const float* __restrict__ outb,
                      float* __restrict__ dst, int nq, int nfeat, int out_n) {
    int i = blockIdx.x * 256 + threadIdx.x;
    if (i >= out_n) return;
    float v = 0.0f;
    if (i < nq) v = qstar[i];
    else if (i - nq < nfeat) v = outb[i - nq];
    dst[i] = v;
}

extern "C" void kernel_launch(void* const* d_in, const int* in_sizes, int n_in,
                              void* d_out, int out_size, void* d_ws, size_t ws_size,
                              hipStream_t stream) {
    constexpr int N = GN, E = GE, B = GB;

    char* ws = (char*)d_ws;
    size_t off = 0;
    auto alloc = [&](size_t bytes) { size_t o = off; off = (off + bytes + 255) & ~(size_t)255; return o; };

    int*   fl     = (int*)  (ws + alloc(19 * 4));
    int*   flagE  = (int*)  (ws + alloc(256));
    int*   flagG  = (int*)  (ws + alloc(256));
    float* counts = (float*)(ws + alloc((size_t)N * 4));
    int*   rowptr = (int*)  (ws + alloc((size_t)(B + 1) * 4));
    float* outbuf = (float*)(ws + alloc((size_t)N * 64 * 4));
    float* agg    = (float*)(ws + alloc((size_t)N * 64 * 4));
    float* qstar  = (float*)(ws + alloc((size_t)B * 128 * 4));
    __hip_bfloat16* h1P = (__hip_bfloat16*)(ws + alloc((size_t)E * 128 * 2));
    __hip_bfloat16* w2P = (__hip_bfloat16*)(ws + alloc((size_t)4096 * 128 * 2));
    __hip_bfloat16* gwp = (__hip_bfloat16*)(ws + alloc((size_t)2 * 12 * 2 * 2 * 512 * 2));

    const int fidx[15]  = {4, 5, 6, 7, 8, 9, 10, 11, 12, 13, 14, 15, 16, 17, 18};
    const int fsize[15] = {75 * 64, 64, 16 * 128, 128, 128 * 4096, 4096, 64,
                           192 * 64, 192 * 64, 192, 192, 256 * 128, 256 * 64, 256, 256};
    float* F[19] = {};
    for (int t = 0; t < 15; ++t) F[fidx[t]] = (float*)(ws + alloc((size_t)fsize[t] * 4));

    DetectArgs da;
    da.src[0] = d_in[0]; da.nhalf[0] = N * 75; da.fi[0] = 0;
    da.src[1] = d_in[1]; da.nhalf[1] = E * 16; da.fi[1] = 1;
    for (int t = 0; t < 15; ++t) { da.src[2 + t] = d_in[fidx[t]]; da.nhalf[2 + t] = fsize[t]; da.fi[2 + t] = fidx[t]; }
    k_detect<<<19, 256, 0, stream>>>(da, (const unsigned int*)d_in[2],
                                     (const unsigned int*)d_in[3], fl, flagE, flagG);

    // cvt list: 14 tensors (w2 -> F[8] dropped; consumed via k_t2 directly)
    const int cidx[14]  = {4, 5, 6, 7, 9, 10, 11, 12, 13, 14, 15, 16, 17, 18};
    const int csize[14] = {75 * 64, 64, 16 * 128, 128, 4096, 64,
                           192 * 64, 192 * 64, 192, 192, 256 * 128, 256 * 64, 256, 256};
    CvtArgs ca;
    int pre = 0;
    for (int t = 0; t < 14; ++t) {
        ca.src[t] = d_in[cidx[t]]; ca.dst[t] = F[cidx[t]]; ca.n[t] = csize[t]; ca.fi[t] = cidx[t];
        ca.pre[t] = pre; pre += (csize[t] + 255) / 256;
    }
    ca.src[14] = d_in[4]; ca.dst[14] = F[4]; ca.n[14] = 0; ca.fi[14] = 4;
    ca.pre[14] = pre; ca.pre[15] = pre;
    k_cvt_all<<<pre, 256, 0, stream>>>(ca, fl);
    k_t2<<<256, 256, 0, stream>>>(d_in[8], w2P, fl + 8);
    k_gpack2<<<12, 256, 0, stream>>>(F[11], F[12], gwp);

    hipMemsetAsync(counts, 0, (size_t)N * 4, stream);
    hipMemsetAsync(agg, 0, (size_t)N * 64 * 4, stream);

    // direct-output mode: write q* and feat_map straight into d_out
    const long long need = (long long)B * 128 + (long long)N * 64;
    const bool direct = (long long)out_size >= need;
    if (direct && (long long)out_size > need)
        hipMemsetAsync((float*)d_out + need, 0, ((size_t)out_size - (size_t)need) * 4, stream);
    if (!direct) hipMemsetAsync(qstar, 0, (size_t)B * 128 * 4, stream);

    k_cnt_rp<<<512 + (B + 1 + 255) / 256, 256, 0, stream>>>(d_in[2], d_in[3], flagE, flagG,
                                                            counts, rowptr);
    k_lin0<<<N / 16, 256, 0, stream>>>(d_in[0], F[4], F[5], outbuf, fl + 0);
    k1_h1<<<E / 16, 256, 0, stream>>>(d_in[1], F[6], F[7], h1P, fl + 1);

    for (int it = 0; it < 3; ++it) {
        k23_fused<<<E / 64, 256, 0, stream>>>(h1P, w2P, F[9], outbuf, d_in[2], flagE, agg);
        float* dst2 = (direct && it == 2) ? ((float*)d_out + (size_t)B * 128) : nullptr;
        k4_gru<<<N / 64, 256, 0, stream>>>(agg, counts, F[10], gwp, F[13], F[14], outbuf, dst2);
    }
    float* dstq = direct ? (float*)d_out : qstar;
    k5_fused<<<B, 256, 0, stream>>>(dstq, F[15], F[16], F[17], F[18], outbuf, rowptr);
    if (!direct)
        k_out<<<(out_size + 255) / 256, 256, 0, stream>>>(qstar, outbuf, (float*)d_out,
                                                          B * 128, N * 64, out_size);
}

// Round 14
// 875.177 us; speedup vs baseline: 1.9690x; 1.0061x over previous
//
#include <hip/hip_runtime.h>
#include <hip/hip_bf16.h>

#define GN 65536
#define GE 131072
#define GB 2048

typedef __attribute__((ext_vector_type(8))) short short8;
typedef __attribute__((ext_vector_type(4))) float floatx4;

static __device__ __forceinline__ float sigm(float x) { return 1.0f / (1.0f + __expf(-x)); }
static __device__ __forceinline__ float bf2f(unsigned short u) {
    union { unsigned int i; float f; } v; v.i = ((unsigned int)u) << 16; return v.f;
}
static __device__ __forceinline__ int geti(const void* p, long long i, int f64) {
    return f64 ? (int)((const long long*)p)[i] : ((const int*)p)[i];
}
static __device__ __forceinline__ float cvtf(const void* p, size_t i, int isf32) {
    return isf32 ? ((const float*)p)[i] : bf2f(((const unsigned short*)p)[i]);
}

// ---- merged detectors: blocks 0-16 float-dtype, 17 edge-i64, 18 graph-i64 ----
struct DetectArgs { const void* src[17]; int nhalf[17]; int fi[17]; };
__global__ void k_detect(DetectArgs a, const unsigned int* __restrict__ pe,
                         const unsigned int* __restrict__ pg,
                         int* __restrict__ flags, int* __restrict__ flagE,
                         int* __restrict__ flagG) {
    __shared__ unsigned int sA[256], sB[256];
    if (blockIdx.x >= 17) {
        const unsigned int* p = (blockIdx.x == 17) ? pe : pg;
        const long long nwords = (blockIdx.x == 17) ? (long long)2 * GE : (long long)GN;
        const long long lim = nwords < 16384 ? nwords : 16384;
        unsigned int acc = 0;
        for (long long w = 1 + 2 * (long long)threadIdx.x; w < lim; w += 512) acc |= p[w];
        sA[threadIdx.x] = acc;
        __syncthreads();
        for (int st = 128; st > 0; st >>= 1) {
            if (threadIdx.x < st) sA[threadIdx.x] |= sA[threadIdx.x + st];
            __syncthreads();
        }
        if (threadIdx.x == 0) *((blockIdx.x == 17) ? flagE : flagG) = (sA[0] == 0u) ? 1 : 0;
        return;
    }
    const unsigned short* p = (const unsigned short*)a.src[blockIdx.x];
    const int n0 = a.nhalf[blockIdx.x];
    const int n = n0 < 16384 ? n0 : 16384;
    unsigned int any = 0, orEven = 0;
    for (int i = threadIdx.x; i < n; i += 256) {
        const unsigned short u = p[i];
        const float av = fabsf(bf2f(u));
        if (!(av <= 1e6f)) any = 1u;
        if ((i & 1) == 0) orEven |= u;
    }
    sA[threadIdx.x] = any; sB[threadIdx.x] = orEven;
    __syncthreads();
    for (int s = 128; s > 0; s >>= 1) {
        if (threadIdx.x < s) {
            sA[threadIdx.x] |= sA[threadIdx.x + s];
            sB[threadIdx.x] |= sB[threadIdx.x + s];
        }
        __syncthreads();
    }
    if (threadIdx.x == 0) flags[a.fi[blockIdx.x]] = (sA[0] || sB[0] == 0u) ? 1 : 0;
}

struct CvtArgs { const void* src[8]; float* dst[8]; int n[8]; int fi[8]; int pre[9]; };

// MEGA-PREP: one dispatch, block-range partitioned; all portions depend only
// on k_detect flags (gpack/lin0/h1 read raw inputs with inline conversion --
// bit-identical values). Portions overlap instead of serializing 6 launches.
//   [0, 8192)            h1 = relu(ef@w1+b1) -> h1P (LDS-restaged coalesced stores)
//   [8192, 12288)        lin0 -> outbuf
//   [12288, 12544)       w2 -> w2P repack
//   [12544, 12556)       GRU weight pack (hi/lo bf16)
//   [12556, 12556+cvtN)  f32 canonicalization of 8 small tensors
//   [cntBase, +521)      edge-count atomics + rowptr binary search
struct PrepArgs {
    const void *w2src, *wih, *whh, *eidx, *gi, *nf, *lw, *lb, *ef, *w1, *b1;
    __hip_bfloat16 *w2P, *gwp, *h1P;
    float *counts, *outbuf;
    int *rowptr;
    CvtArgs ca;
    int cvtN, cntBase;
    const int *fl, *flagE, *flagG;
};
__global__ __launch_bounds__(256) void k_prep(PrepArgs p) {
    __shared__ __align__(16) char smem[(75 * 66 + 16 * 76) * 4];
    const int b = blockIdx.x;
    const int tid = threadIdx.x;

    if (b < 8192) {                              // ---- h1 ----
        const int eb0 = b * 16;
        const int f1 = p.fl[1], f6 = p.fl[6], f7 = p.fl[7];
        float* efs = (float*)smem;               // [16][17]
        __hip_bfloat16* sh1 = (__hip_bfloat16*)(smem + 16 * 17 * 4);  // [2048]
        {
            const int e = tid >> 4, i = tid & 15;
            efs[e * 17 + i] = cvtf(p.ef, (size_t)(eb0 + e) * 16 + i, f1);
        }
        __syncthreads();
        const int j = tid & 127, half = tid >> 7;
        float wcol[16];
        #pragma unroll
        for (int i = 0; i < 16; ++i) wcol[i] = cvtf(p.w1, (size_t)i * 128 + j, f6);
        const float bj = cvtf(p.b1, j, f7);
        const int kk = j >> 5, qd = (j >> 3) & 3, jj = j & 7;
        #pragma unroll
        for (int eo = 0; eo < 8; ++eo) {
            const int le = half * 8 + eo;
            float acc = bj;
            #pragma unroll
            for (int i = 0; i < 16; ++i) acc = fmaf(efs[le * 17 + i], wcol[i], acc);
            sh1[kk * 512 + (qd * 16 + le) * 8 + jj] = __float2bfloat16(fmaxf(acc, 0.0f));
        }
        __syncthreads();
        const int kk2 = tid >> 6, idx = (tid & 63) * 8;
        const int ebk = eb0 >> 6, rb = (eb0 & 63) >> 4;
        *(short8*)(p.h1P + (size_t)ebk * 8192 + (kk2 * 4 + rb) * 512 + idx) =
            *(const short8*)(sh1 + kk2 * 512 + idx);
        return;
    }
    if (b < 12288) {                             // ---- lin0 ----
        const int nb0 = (b - 8192) * 16;
        const int f0 = p.fl[0], f4 = p.fl[4], f5 = p.fl[5];
        float* sw = (float*)smem;                // [75][66]
        float* snf = sw + 75 * 66;               // [16][76]
        for (int i = tid; i < 75 * 64; i += 256) sw[(i >> 6) * 66 + (i & 63)] = cvtf(p.lw, i, f4);
        for (int i = tid; i < 16 * 75; i += 256) {
            const int nn = i / 75, ii = i % 75;
            snf[nn * 76 + ii] = cvtf(p.nf, (size_t)(nb0 + nn) * 75 + ii, f0);
        }
        __syncthreads();
        const int ln = tid >> 6, d = tid & 63;
        const float bd = cvtf(p.lb, d, f5);
        #pragma unroll
        for (int g = 0; g < 4; ++g) {
            const int nn = ln * 4 + g;
            float acc = bd;
            #pragma unroll
            for (int i = 0; i < 75; ++i) acc = fmaf(snf[nn * 76 + i], sw[i * 66 + d], acc);
            p.outbuf[(size_t)(nb0 + nn) * 64 + d] = fmaxf(acc, 0.0f);
        }
        return;
    }
    if (b < 12544) {                             // ---- w2 -> w2P ----
        const int tid8 = (b - 12288) * 256 + tid;
        const int quad = tid8 & 3, lr = (tid8 >> 2) & 15, rb = (tid8 >> 6) & 7,
                  kk = (tid8 >> 9) & 3, t = tid8 >> 11;
        const int n = t * 128 + rb * 16 + lr;
        const int k0 = kk * 32 + quad * 8;
        const int f8 = p.fl[8];
        short8 v;
        #pragma unroll
        for (int j = 0; j < 8; ++j) {
            const float f = cvtf(p.w2src, (size_t)(k0 + j) * 4096 + n, f8);
            const __hip_bfloat16 bb = __float2bfloat16(f);
            v[j] = *(const short*)&bb;
        }
        *(short8*)(p.w2P + (size_t)tid8 * 8) = v;
        return;
    }
    if (b < 12556) {                             // ---- GRU weight pack ----
        const int t = (b - 12544) * 256 + tid;
        if (t >= 3072) return;
        const int lane = t & 63;
        const int kk = (t >> 6) & 1;
        const int nb = (t >> 7) % 12;
        const int mat = t / 1536;
        const void* W = mat ? p.whh : p.wih;
        const int fm = mat ? p.fl[12] : p.fl[11];
        const int c = nb * 16 + (lane & 15);
        const int k0 = kk * 32 + (lane >> 4) * 8;
        short8 hi, lo;
        #pragma unroll
        for (int j = 0; j < 8; ++j) {
            const float v = cvtf(W, (size_t)c * 64 + k0 + j, fm);
            const __hip_bfloat16 bh = __float2bfloat16(v);
            hi[j] = *(const short*)&bh;
            const __hip_bfloat16 bl = __float2bfloat16(v - __bfloat162float(bh));
            lo[j] = *(const short*)&bl;
        }
        const size_t base = (size_t)(((mat * 12 + nb) * 2 + kk) * 2);
        *(short8*)(p.gwp + (base + 0) * 512 + lane * 8) = hi;
        *(short8*)(p.gwp + (base + 1) * 512 + lane * 8) = lo;
        return;
    }
    if (b < 12556 + p.cvtN) {                    // ---- f32 canonicalization ----
        const int bb = b - 12556;
        int t = 0;
        while (t < 7 && bb >= p.ca.pre[t + 1]) ++t;
        const int i = (bb - p.ca.pre[t]) * 256 + tid;
        if (i >= p.ca.n[t]) return;
        const int f = p.fl[p.ca.fi[t]];
        p.ca.dst[t][i] = f ? ((const float*)p.ca.src[t])[i]
                           : bf2f(((const unsigned short*)p.ca.src[t])[i]);
        return;
    }
    {                                            // ---- counts + rowptr ----
        const int bb = b - p.cntBase;
        if (bb < 512) {
            const int e = bb * 256 + tid;
            atomicAdd(&p.counts[geti(p.eidx, (long long)GE + e, *p.flagE)], 1.0f);
            return;
        }
        const int g = (bb - 512) * 256 + tid;
        if (g > GB) return;
        const int f64 = *p.flagG;
        int lo = 0, hi = GN;
        while (lo < hi) { int mid = (lo + hi) >> 1; if (geti(p.gi, mid, f64) < g) lo = mid + 1; else hi = mid; }
        p.rowptr[g] = lo;
    }
}

// FUSED NNConv v13b (r13-verified best: min-waves 3, VGPR 84, ~160us).
__global__ __launch_bounds__(256, 3) void k23_fused(const __hip_bfloat16* __restrict__ h1P,
                                                 const __hip_bfloat16* __restrict__ w2P,
                                                 const float* __restrict__ b2,
                                                 const float* __restrict__ out,
                                                 const void* __restrict__ eidx,
                                                 const int* __restrict__ fi64,
                                                 float* __restrict__ agg) {
    __shared__ __align__(16) __hip_bfloat16 As[64 * 128];   // 16 KB; aliased as merge buf
    __shared__ float yT[64][65];                            // 16.6 KB [d][e]
    __shared__ int sdx[64];                                 // dst indices
    const int tid = threadIdx.x;
    const int e0 = blockIdx.x * 64;
    const int f64 = *fi64;

    const int wave = tid >> 6, lane = tid & 63;
    const int wn = wave * 32;              // 4 N-slices of 32 cols
    const int lr = lane & 15, quad = lane >> 4;

    if (tid < 64) sdx[tid] = geti(eidx, (long long)GE + e0 + tid, f64);
    // stage As: flat 16KB coalesced copy (h1P is already the LDS image)
    {
        const short8* s8 = (const short8*)(h1P + (size_t)blockIdx.x * 8192);
        short8* d8 = (short8*)As;
        #pragma unroll
        for (int i = 0; i < 4; ++i) d8[i * 256 + tid] = s8[i * 256 + tid];
    }
    // stage yT[d][e] = out[src[e]][d]
    {
        const int e = tid >> 2, d0 = (tid & 3) * 16;
        const int s = geti(eidx, e0 + e, f64);
        const float* srow = out + (size_t)s * 64 + d0;
        #pragma unroll
        for (int j = 0; j < 4; ++j) {
            float4 v = *(const float4*)(srow + j * 4);
            yT[d0 + j * 4 + 0][e] = v.x;
            yT[d0 + j * 4 + 1][e] = v.y;
            yT[d0 + j * 4 + 2][e] = v.z;
            yT[d0 + j * 4 + 3][e] = v.w;
        }
    }
    __syncthreads();

    const int lin = (lr * 4 + quad) * 8;   // lane offset inside a 512-elem group
    const char* Ab = (const char*)As + lane * 16;   // lane-consecutive A base
    float msum[4][2][4] = {};

#define K23_LOADB(dst, tt)                                                      \
    _Pragma("unroll")                                                           \
    for (int kk = 0; kk < 4; ++kk) {                                            \
        _Pragma("unroll")                                                       \
        for (int nt = 0; nt < 2; ++nt) {                                        \
            const int g = ((tt) * 4 + kk) * 8 + (wn >> 4) + nt;                 \
            dst[kk][nt] = *(const short8*)(w2P + (size_t)g * 512 + lin);        \
        }                                                                       \
    }                                                                           \
    __builtin_amdgcn_sched_barrier(0);

#define K23_BODY(tt, buf) {                                                     \
    const int n0 = (tt) * 128;                                                  \
    const int dcur = (n0 + wn) >> 6;                                            \
    const float b2v0 = b2[n0 + wn + lr];                                        \
    const float b2v1 = b2[n0 + wn + 16 + lr];                                   \
    floatx4 acc[4][2] = {};                                                     \
    _Pragma("unroll")                                                           \
    for (int kk = 0; kk < 4; ++kk) {                                            \
        short8 a0, a1, a2, a3;                                                  \
        a0 = *(const short8*)(Ab + kk * 4096 + 0 * 1024);                       \
        a1 = *(const short8*)(Ab + kk * 4096 + 1 * 1024);                       \
        a2 = *(const short8*)(Ab + kk * 4096 + 2 * 1024);                       \
        a3 = *(const short8*)(Ab + kk * 4096 + 3 * 1024);                       \
        __builtin_amdgcn_s_setprio(1);                                          \
        acc[0][0] = __builtin_amdgcn_mfma_f32_16x16x32_bf16(a0, buf[kk][0], acc[0][0], 0, 0, 0); \
        acc[0][1] = __builtin_amdgcn_mfma_f32_16x16x32_bf16(a0, buf[kk][1], acc[0][1], 0, 0, 0); \
        acc[1][0] = __builtin_amdgcn_mfma_f32_16x16x32_bf16(a1, buf[kk][0], acc[1][0], 0, 0, 0); \
        acc[1][1] = __builtin_amdgcn_mfma_f32_16x16x32_bf16(a1, buf[kk][1], acc[1][1], 0, 0, 0); \
        acc[2][0] = __builtin_amdgcn_mfma_f32_16x16x32_bf16(a2, buf[kk][0], acc[2][0], 0, 0, 0); \
        acc[2][1] = __builtin_amdgcn_mfma_f32_16x16x32_bf16(a2, buf[kk][1], acc[2][1], 0, 0, 0); \
        acc[3][0] = __builtin_amdgcn_mfma_f32_16x16x32_bf16(a3, buf[kk][0], acc[3][0], 0, 0, 0); \
        acc[3][1] = __builtin_amdgcn_mfma_f32_16x16x32_bf16(a3, buf[kk][1], acc[3][1], 0, 0, 0); \
        __builtin_amdgcn_s_setprio(0);                                          \
    }                                                                           \
    _Pragma("unroll")                                                           \
    for (int mt = 0; mt < 4; ++mt) {                                            \
        _Pragma("unroll")                                                       \
        for (int r = 0; r < 4; ++r) {                                           \
            const float yv = yT[dcur][mt * 16 + quad * 4 + r];                  \
            msum[mt][0][r] = fmaf(yv, acc[mt][0][r] + b2v0, msum[mt][0][r]);    \
            msum[mt][1][r] = fmaf(yv, acc[mt][1][r] + b2v1, msum[mt][1][r]);    \
        }                                                                       \
    }                                                                           \
}

    short8 bA[4][2], bB[4][2];
    K23_LOADB(bA, 0)
    #pragma unroll 1
    for (int t = 0; t < 32; t += 2) {
        K23_LOADB(bB, t + 1)          // in flight across BODY(t)
        K23_BODY(t, bA)
        if (t + 2 < 32) { K23_LOADB(bA, t + 2) }  // in flight across BODY(t+1)
        K23_BODY(t + 1, bB)
    }
#undef K23_LOADB
#undef K23_BODY

    // merged epilogue: fold wave-pair (wn, wn+64) partials in LDS, then
    // one coalesced atomicAdd set. As (16KB) aliased as 64x64 f32 merge buf.
    __syncthreads();                       // all waves done with As/yT
    float* mg = (float*)As;
    const int fb = (wn & 32);
    if (wave < 2) {
        #pragma unroll
        for (int mt = 0; mt < 4; ++mt)
            #pragma unroll
            for (int r = 0; r < 4; ++r)
                #pragma unroll
                for (int nt = 0; nt < 2; ++nt)
                    mg[(mt * 16 + quad * 4 + r) * 64 + fb + nt * 16 + lr] = msum[mt][nt][r];
    }
    __syncthreads();
    if (wave >= 2) {
        #pragma unroll
        for (int mt = 0; mt < 4; ++mt)
            #pragma unroll
            for (int r = 0; r < 4; ++r)
                #pragma unroll
                for (int nt = 0; nt < 2; ++nt)
                    mg[(mt * 16 + quad * 4 + r) * 64 + fb + nt * 16 + lr] += msum[mt][nt][r];
    }
    __syncthreads();
    #pragma unroll
    for (int i = 0; i < 16; ++i) {
        const int o = i * 256 + tid;
        const int row = o >> 6, col = o & 63;
        atomicAdd(&agg[(size_t)sdx[row] * 64 + col], mg[o]);
    }
}

// GRU v5: MFMA gate GEMMs + in-place agg re-zero; optional dual-write of the
// final h into d_out's feat_map region.
__global__ __launch_bounds__(256) void k4_gru(float* __restrict__ agg,
                                              const float* __restrict__ counts,
                                              const float* __restrict__ cbias,
                                              const __hip_bfloat16* __restrict__ gwp,
                                              const float* __restrict__ b_ih,
                                              const float* __restrict__ b_hh,
                                              float* __restrict__ out,
                                              float* __restrict__ dst2) {
    const int wv = threadIdx.x >> 6, lane = threadIdx.x & 63;
    const int lr = lane & 15, quad = lane >> 4;
    const int wnb0 = blockIdx.x * 64 + wv * 16;
    const int node = wnb0 + lr;

    const float rcnt = 1.0f / fmaxf(counts[node], 1.0f);
    float* ap = agg + (size_t)node * 64;
    const float* hp = out + (size_t)node * 64;
    short8 am[2], ah[2];
    #pragma unroll
    for (int kk = 0; kk < 2; ++kk) {
        const int k0 = kk * 32 + quad * 8;
        #pragma unroll
        for (int j = 0; j < 8; ++j) {
            const float mv = fmaxf(ap[k0 + j] * rcnt + cbias[k0 + j], 0.0f);
            const __hip_bfloat16 mb = __float2bfloat16(mv);
            am[kk][j] = *(const short*)&mb;
            const __hip_bfloat16 hb = __float2bfloat16(hp[k0 + j]);
            ah[kk][j] = *(const short*)&hb;
        }
    }
    // zero agg for the next NNConv iteration (replaces memset dispatch)
    {
        const float4 z = {0.0f, 0.0f, 0.0f, 0.0f};
        #pragma unroll
        for (int kk = 0; kk < 2; ++kk) {
            const int k0 = kk * 32 + quad * 8;
            *(float4*)(ap + k0) = z;
            *(float4*)(ap + k0 + 4) = z;
        }
    }

    floatx4 ai[12] = {}, ahh[12] = {};
    #pragma unroll
    for (int nb = 0; nb < 12; ++nb) {
        #pragma unroll
        for (int kk = 0; kk < 2; ++kk) {
            #pragma unroll
            for (int part = 0; part < 2; ++part) {
                const short8 bi = *(const short8*)(gwp + (size_t)(((0 * 12 + nb) * 2 + kk) * 2 + part) * 512 + lane * 8);
                ai[nb] = __builtin_amdgcn_mfma_f32_16x16x32_bf16(am[kk], bi, ai[nb], 0, 0, 0);
                const short8 bh = *(const short8*)(gwp + (size_t)(((1 * 12 + nb) * 2 + kk) * 2 + part) * 512 + lane * 8);
                ahh[nb] = __builtin_amdgcn_mfma_f32_16x16x32_bf16(ah[kk], bh, ahh[nb], 0, 0, 0);
            }
        }
    }

    #pragma unroll
    for (int f = 0; f < 4; ++f) {
        const int d = f * 16 + lr;
        const float bir = b_ih[d],       bhr = b_hh[d];
        const float biz = b_ih[64 + d],  bhz = b_hh[64 + d];
        const float bin = b_ih[128 + d], bhn = b_hh[128 + d];
        #pragma unroll
        for (int r = 0; r < 4; ++r) {
            const int row = wnb0 + quad * 4 + r;
            const float rr = sigm(ai[f][r] + bir + ahh[f][r] + bhr);
            const float zz = sigm(ai[f + 4][r] + biz + ahh[f + 4][r] + bhz);
            const float nn = tanhf(ai[f + 8][r] + bin + rr * (ahh[f + 8][r] + bhn));
            const float hd = out[(size_t)row * 64 + d];
            const float hnew = (1.0f - zz) * nn + zz * hd;
            out[(size_t)row * 64 + d] = hnew;
            if (dst2) dst2[(size_t)row * 64 + d] = hnew;
        }
    }
}

// FUSED Set2Set: all 3 processing steps in ONE launch; writes q* directly to dstq.
__global__ __launch_bounds__(256) void k5_fused(float* __restrict__ dstq,
                                                const float* __restrict__ w_ih,
                                                const float* __restrict__ w_hh,
                                                const float* __restrict__ b_ih,
                                                const float* __restrict__ b_hh,
                                                const float* __restrict__ out,
                                                const int* __restrict__ rowptr) {
    const int g = blockIdx.x;
    const int j = threadIdx.x;
    __shared__ float qs[128], hv[64], gates[256];
    __shared__ float smw[4], sSw[4], srw[4][64];
    if (j < 128) qs[j] = 0.0f;
    if (j < 64) hv[j] = 0.0f;
    float creg = 0.0f;               // cs state (threads j<64)
    const int wv = j >> 6, lane = j & 63;
    const int start = rowptr[g], end = rowptr[g + 1];
    const float bsum = b_ih[j] + b_hh[j];

    for (int step = 0; step < 3; ++step) {
        __syncthreads();             // qs/hv (and smw/srw reuse) ready
        float acc = bsum;
        for (int k4 = 0; k4 < 128; k4 += 4) {
            float4 v = *(const float4*)(w_ih + (size_t)j * 128 + k4);
            const float* pv = (const float*)&v;
            #pragma unroll
            for (int t = 0; t < 4; ++t) acc += qs[k4 + t] * pv[t];
        }
        for (int k4 = 0; k4 < 64; k4 += 4) {
            float4 v = *(const float4*)(w_hh + (size_t)j * 64 + k4);
            const float* pv = (const float*)&v;
            #pragma unroll
            for (int t = 0; t < 4; ++t) acc += hv[k4 + t] * pv[t];
        }
        gates[j] = acc;
        __syncthreads();
        if (j < 64) {
            const float ig = sigm(gates[j]);
            const float fg = sigm(gates[64 + j]);
            const float gg = tanhf(gates[128 + j]);
            const float og = sigm(gates[192 + j]);
            creg = fg * creg + ig * gg;
            const float h = og * tanhf(creg);
            hv[j] = h;
            qs[j] = h;
        }
        __syncthreads();
        // attention: wave wv handles nodes start+wv, start+wv+4, ...
        const float q = hv[lane];
        float m = -3.4e38f, S = 0.0f, racc = 0.0f;
        for (int n = start + wv; n < end; n += 4) {
            const float ov = out[(size_t)n * 64 + lane];
            float p = ov * q;
            #pragma unroll
            for (int off = 1; off < 64; off <<= 1) p += __shfl_xor(p, off);
            if (p > m) {
                const float sc = __expf(m - p);
                S = S * sc + 1.0f;
                racc = racc * sc + ov;
                m = p;
            } else {
                const float w = __expf(p - m);
                S += w;
                racc += w * ov;
            }
        }
        if (lane == 0) { smw[wv] = m; sSw[wv] = S; }
        srw[wv][lane] = racc;
        __syncthreads();
        if (wv == 0) {
            const float mstar = fmaxf(fmaxf(smw[0], smw[1]), fmaxf(smw[2], smw[3]));
            float Ssum = 0.0f, rsum = 0.0f;
            #pragma unroll
            for (int i = 0; i < 4; ++i) {
                const float sc = __expf(smw[i] - mstar);   // empty wave: exp(-huge)=0
                Ssum += sSw[i] * sc;
                rsum += srw[i][lane] * sc;
            }
            qs[64 + lane] = rsum / (Ssum + 1e-16f);
        }
    }
    __syncthreads();
    if (j < 128) dstq[(size_t)g * 128 + j] = qs[j];
}

__global__ void k_out(const float* __restrict__ qstar, const float* __restrict__ outb,
                      float* __restrict__ dst, int nq, int nfeat, int out_n) {
    int i = blockIdx.x * 256 + threadIdx.x;
    if (i >= out_n) return;
    float v = 0.0f;
    if (i < nq) v = qstar[i];
    else if (i - nq < nfeat) v = outb[i - nq];
    dst[i] = v;
}

extern "C" void kernel_launch(void* const* d_in, const int* in_sizes, int n_in,
                              void* d_out, int out_size, void* d_ws, size_t ws_size,
                              hipStream_t stream) {
    constexpr int N = GN, E = GE, B = GB;

    char* ws = (char*)d_ws;
    size_t off = 0;
    auto alloc = [&](size_t bytes) { size_t o = off; off = (off + bytes + 255) & ~(size_t)255; return o; };

    int*   fl     = (int*)  (ws + alloc(19 * 4));
    int*   flagE  = (int*)  (ws + alloc(256));
    int*   flagG  = (int*)  (ws + alloc(256));
    float* counts = (float*)(ws + alloc((size_t)N * 4));
    int*   rowptr = (int*)  (ws + alloc((size_t)(B + 1) * 4));
    float* outbuf = (float*)(ws + alloc((size_t)N * 64 * 4));
    float* agg    = (float*)(ws + alloc((size_t)N * 64 * 4));
    float* qstar  = (float*)(ws + alloc((size_t)B * 128 * 4));
    __hip_bfloat16* h1P = (__hip_bfloat16*)(ws + alloc((size_t)E * 128 * 2));
    __hip_bfloat16* w2P = (__hip_bfloat16*)(ws + alloc((size_t)4096 * 128 * 2));
    __hip_bfloat16* gwp = (__hip_bfloat16*)(ws + alloc((size_t)2 * 12 * 2 * 2 * 512 * 2));

    const int fidx[15]  = {4, 5, 6, 7, 8, 9, 10, 11, 12, 13, 14, 15, 16, 17, 18};
    const int fsize[15] = {75 * 64, 64, 16 * 128, 128, 128 * 4096, 4096, 64,
                           192 * 64, 192 * 64, 192, 192, 256 * 128, 256 * 64, 256, 256};
    float* F[19] = {};
    for (int t = 0; t < 15; ++t) F[fidx[t]] = (float*)(ws + alloc((size_t)fsize[t] * 4));

    DetectArgs da;
    da.src[0] = d_in[0]; da.nhalf[0] = N * 75; da.fi[0] = 0;
    da.src[1] = d_in[1]; da.nhalf[1] = E * 16; da.fi[1] = 1;
    for (int t = 0; t < 15; ++t) { da.src[2 + t] = d_in[fidx[t]]; da.nhalf[2 + t] = fsize[t]; da.fi[2 + t] = fidx[t]; }

    hipMemsetAsync(counts, 0, (size_t)N * 4, stream);
    hipMemsetAsync(agg, 0, (size_t)N * 64 * 4, stream);

    // direct-output mode: write q* and feat_map straight into d_out
    const long long need = (long long)B * 128 + (long long)N * 64;
    const bool direct = (long long)out_size >= need;
    if (direct && (long long)out_size > need)
        hipMemsetAsync((float*)d_out + need, 0, ((size_t)out_size - (size_t)need) * 4, stream);
    if (!direct) hipMemsetAsync(qstar, 0, (size_t)B * 128 * 4, stream);

    k_detect<<<19, 256, 0, stream>>>(da, (const unsigned int*)d_in[2],
                                     (const unsigned int*)d_in[3], fl, flagE, flagG);

    // mega-prep: h1 + lin0 + w2P + gwp + cvt(8 tensors) + counts/rowptr
    PrepArgs pa;
    pa.w2src = d_in[8]; pa.wih = d_in[11]; pa.whh = d_in[12];
    pa.eidx = d_in[2]; pa.gi = d_in[3];
    pa.nf = d_in[0]; pa.lw = d_in[4]; pa.lb = d_in[5];
    pa.ef = d_in[1]; pa.w1 = d_in[6]; pa.b1 = d_in[7];
    pa.w2P = w2P; pa.gwp = gwp; pa.h1P = h1P;
    pa.counts = counts; pa.outbuf = outbuf; pa.rowptr = rowptr;
    pa.fl = fl; pa.flagE = flagE; pa.flagG = flagG;
    const int cidx[8]  = {9, 10, 13, 14, 15, 16, 17, 18};
    const int csize[8] = {4096, 64, 192, 192, 256 * 128, 256 * 64, 256, 256};
    int pre = 0;
    for (int t = 0; t < 8; ++t) {
        pa.ca.src[t] = d_in[cidx[t]]; pa.ca.dst[t] = F[cidx[t]];
        pa.ca.n[t] = csize[t]; pa.ca.fi[t] = cidx[t];
        pa.ca.pre[t] = pre; pre += (csize[t] + 255) / 256;
    }
    pa.ca.pre[8] = pre;
    pa.cvtN = pre;
    pa.cntBase = 12556 + pre;
    const int totalBlocks = pa.cntBase + 512 + (B + 1 + 255) / 256;
    k_prep<<<totalBlocks, 256, 0, stream>>>(pa);

    for (int it = 0; it < 3; ++it) {
        k23_fused<<<E / 64, 256, 0, stream>>>(h1P, w2P, F[9], outbuf, d_in[2], flagE, agg);
        float* dst2 = (direct && it == 2) ? ((float*)d_out + (size_t)B * 128) : nullptr;
        k4_gru<<<N / 64, 256, 0, stream>>>(agg, counts, F[10], gwp, F[13], F[14], outbuf, dst2);
    }
    float* dstq = direct ? (float*)d_out : qstar;
    k5_fused<<<B, 256, 0, stream>>>(dstq, F[15], F[16], F[17], F[18], outbuf, rowptr);
    if (!direct)
        k_out<<<(out_size + 255) / 256, 256, 0, stream>>>(qstar, outbuf, (float*)d_out,
                                                          B * 128, N * 64, out_size);
}